// Round 1
// baseline (157.238 us; speedup 1.0000x reference)
//
#include <hip/hip_runtime.h>

// Problem constants (from reference setup_inputs):
//   image:  (B=4, H=512, W=640, C=16) fp32
//   depth:  (B, H, W) fp32
//   proj:   (B, 4, 4) fp32
//   out:    (B, H, W, C) fp32
constexpr int B  = 4;
constexpr int H  = 512;
constexpr int Wd = 640;
constexpr int C  = 16;          // 4 float4 groups per pixel
constexpr int NPIX = B * H * Wd;
constexpr int NTHREADS = NPIX * (C / 4);   // one thread per (pixel, c4)

__global__ __launch_bounds__(256) void depth_project_kernel(
    const float* __restrict__ image,
    const float* __restrict__ depth,
    const float* __restrict__ proj,
    float4* __restrict__ out)
{
    int tid = blockIdx.x * blockDim.x + threadIdx.x;
    if (tid >= NTHREADS) return;

    int c4  = tid & 3;        // which float4 group of the 16 channels
    int pix = tid >> 2;       // linear pixel index b*H*W + h*W + w
    int w   = pix % Wd;
    int t   = pix / Wd;
    int h   = t % H;
    int b   = t / H;

    // Projection: coords = ((R @ [x,y,1]) * d + t)[:2] / (...)[2]
    const float* P = proj + b * 16;   // row-major 4x4
    float x = (float)w;
    float y = (float)h;
    float d = depth[pix];

    float sx = (P[0] * x + P[1] * y + P[2])  * d + P[3];
    float sy = (P[4] * x + P[5] * y + P[6])  * d + P[7];
    float sz = (P[8] * x + P[9] * y + P[10]) * d + P[11];
    float cx = sx / sz;
    float cy = sy / sz;

    // Bilinear weights + validity (zero weight outside, clamp index for gather)
    float x0f = floorf(cx), y0f = floorf(cy);
    float wx1 = cx - x0f,   wy1 = cy - y0f;
    float wx0 = 1.0f - wx1, wy0 = 1.0f - wy1;
    int x0 = (int)x0f, y0 = (int)y0f;
    int x1 = x0 + 1,   y1 = y0 + 1;

    float vx0 = (x0 >= 0 && x0 < Wd) ? 1.0f : 0.0f;
    float vx1 = (x1 >= 0 && x1 < Wd) ? 1.0f : 0.0f;
    float vy0 = (y0 >= 0 && y0 < H)  ? 1.0f : 0.0f;
    float vy1 = (y1 >= 0 && y1 < H)  ? 1.0f : 0.0f;

    int x0c = min(max(x0, 0), Wd - 1);
    int x1c = min(max(x1, 0), Wd - 1);
    int y0c = min(max(y0, 0), H - 1);
    int y1c = min(max(y1, 0), H - 1);

    float w00 = wy0 * wx0 * vy0 * vx0;
    float w01 = wy0 * wx1 * vy0 * vx1;
    float w10 = wy1 * wx0 * vy1 * vx0;
    float w11 = wy1 * wx1 * vy1 * vx1;

    // Gather 4 corners (float4 per thread = 16B; 4 lanes cover one 64B pixel)
    const float4* img4 = (const float4*)image;
    int base_b = b * (H * Wd * 4);   // float4 units; max 5.2M fits int
    float4 g00 = img4[base_b + (y0c * Wd + x0c) * 4 + c4];
    float4 g01 = img4[base_b + (y0c * Wd + x1c) * 4 + c4];
    float4 g10 = img4[base_b + (y1c * Wd + x0c) * 4 + c4];
    float4 g11 = img4[base_b + (y1c * Wd + x1c) * 4 + c4];

    float4 r;
    r.x = g00.x * w00 + g01.x * w01 + g10.x * w10 + g11.x * w11;
    r.y = g00.y * w00 + g01.y * w01 + g10.y * w10 + g11.y * w11;
    r.z = g00.z * w00 + g01.z * w01 + g10.z * w10 + g11.z * w11;
    r.w = g00.w * w00 + g01.w * w01 + g10.w * w10 + g11.w * w11;

    out[tid] = r;   // perfectly coalesced: lane i -> 16B at tid*16
}

extern "C" void kernel_launch(void* const* d_in, const int* in_sizes, int n_in,
                              void* d_out, int out_size, void* d_ws, size_t ws_size,
                              hipStream_t stream) {
    const float* image = (const float*)d_in[0];
    const float* depth = (const float*)d_in[1];
    const float* proj  = (const float*)d_in[2];
    float4* out = (float4*)d_out;

    constexpr int block = 256;
    constexpr int grid  = (NTHREADS + block - 1) / block;   // 20480 blocks
    depth_project_kernel<<<grid, block, 0, stream>>>(image, depth, proj, out);
}